// Round 4
// baseline (73.036 us; speedup 1.0000x reference)
//
#include <hip/hip_runtime.h>
#include <hip/hip_bf16.h>
#include <math.h>

// B=128, F_IN=1000, D=512, K=10, C=5, T=1000, TAU=0.1
// Contraction: logits_s[b,t,k] = sum_c v[b,c,t]*M[b,c,k], M = h @ W_mlp.
// 3 kernels (minimum chain: adapt GEMM -> channel GEMM -> epilogue):
//   kA  : adapt k-split partials pA[s][b][e]; also zero-inits atomic accums.
//   kG2 : reduce pA->r_b in LDS, channel GEMM in regs, gate/M reduced via
//         wave-shfl + global atomicAdd (no pB intermediate at all).
//   kC  : pv=sigmoid(gate), per-(b,t) gumbel-sigmoid, softmax_c, MLP, softmax_k.

// ---- adapt partials: pA[s][b][e]; s=10 splits of 100 k, 4 b per block ----
__global__ __launch_bounds__(256) void kA(const float* __restrict__ feats,
                                          const float* __restrict__ W_adapt,
                                          float* __restrict__ pA,
                                          float* __restrict__ accums /*7040*/) {
    if (blockIdx.x == 0 && blockIdx.y == 0) {
        for (int i = threadIdx.x; i < 7040; i += 256) accums[i] = 0.f;
    }
    int b0 = blockIdx.x * 4;          // 32 b-tiles
    int s  = blockIdx.y;              // 10 k-splits
    int k0 = s * 100;
    int e2 = threadIdx.x * 2;         // float2 over e
    float2 acc[4] = {};
    #pragma unroll 2
    for (int k = 0; k < 100; ++k) {
        float2 w = *(const float2*)&W_adapt[(k0 + k) * 512 + e2];
        #pragma unroll
        for (int j = 0; j < 4; ++j) {
            float f = feats[(b0 + j) * 1000 + k0 + k];   // wave-uniform
            acc[j].x = fmaf(f, w.x, acc[j].x);
            acc[j].y = fmaf(f, w.y, acc[j].y);
        }
    }
    #pragma unroll
    for (int j = 0; j < 4; ++j)
        *(float2*)&pA[(s * 128 + b0 + j) * 512 + e2] = acc[j];
}

// ---- channel GEMM + gate/M atomics ----
// grid (bt 16, ec 4, c 5) = 320 blocks, 256 thr. LDS: r_b slice [8b][512d].
// wave w (=tid>>6) owns b-pair j0=2w; lanes = 64 float2-e's (128 e per block).
__global__ __launch_bounds__(256) void kG2(const float* __restrict__ pA,
                                           const float* __restrict__ b_adapt,
                                           const float* __restrict__ W_ch,
                                           const float* __restrict__ b_ch,
                                           const float* __restrict__ W_gate,
                                           const float* __restrict__ W_mlp,
                                           float* __restrict__ gacc,
                                           float* __restrict__ Macc) {
    __shared__ float rb[8 * 512];
    int b0 = blockIdx.x * 8;
    int e0 = blockIdx.y * 128;
    int c  = blockIdx.z;
    int tid = threadIdx.x;

    // phase A: r_b[b0+j][d] = relu(b_adapt + sum_s pA)  (coalesced, 2x-redundant)
    #pragma unroll
    for (int it = 0; it < 16; ++it) {
        int idx = it * 256 + tid;        // j*512+d
        int j = idx >> 9, d = idx & 511;
        float g = b_adapt[d];
        #pragma unroll
        for (int sp = 0; sp < 10; ++sp)
            g += pA[sp * 65536 + (b0 + j) * 512 + d];
        rb[idx] = fmaxf(g, 0.f);
    }
    __syncthreads();

    // phase B: h for (2 b's, 2 e's) per thread, all in registers
    int le = tid & 63;
    int j0 = (tid >> 6) * 2;
    int e  = e0 + le * 2;
    const float* wcol = &W_ch[(size_t)c * 512 * 512 + e];
    const float* rb0 = &rb[j0 * 512];
    const float* rb1 = &rb[j0 * 512 + 512];
    float hx0 = 0.f, hy0 = 0.f, hx1 = 0.f, hy1 = 0.f;
    #pragma unroll 4
    for (int d = 0; d < 512; ++d) {
        float2 w = *(const float2*)&wcol[(size_t)d * 512];
        float r0 = rb0[d], r1 = rb1[d];                 // LDS broadcast
        hx0 = fmaf(r0, w.x, hx0); hy0 = fmaf(r0, w.y, hy0);
        hx1 = fmaf(r1, w.x, hx1); hy1 = fmaf(r1, w.y, hy1);
    }
    float2 bc = *(const float2*)&b_ch[c * 512 + e];
    hx0 = fmaxf(hx0 + bc.x, 0.f); hy0 = fmaxf(hy0 + bc.y, 0.f);
    hx1 = fmaxf(hx1 + bc.x, 0.f); hy1 = fmaxf(hy1 + bc.y, 0.f);

    float2 wg = *(const float2*)&W_gate[c * 512 + e];
    float gs0 = hx0 * wg.x + hy0 * wg.y;
    float gs1 = hx1 * wg.x + hy1 * wg.y;
    float am0[10], am1[10];
    const float* wm = &W_mlp[e * 10];
    #pragma unroll
    for (int k = 0; k < 10; ++k) {
        am0[k] = hx0 * wm[k] + hy0 * wm[10 + k];
        am1[k] = hx1 * wm[k] + hy1 * wm[10 + k];
    }
    #pragma unroll
    for (int off = 32; off; off >>= 1) {
        gs0 += __shfl_xor(gs0, off);
        gs1 += __shfl_xor(gs1, off);
        #pragma unroll
        for (int k = 0; k < 10; ++k) {
            am0[k] += __shfl_xor(am0[k], off);
            am1[k] += __shfl_xor(am1[k], off);
        }
    }
    if (le == 0) {
        int p0 = (b0 + j0) * 5 + c, p1 = (b0 + j0 + 1) * 5 + c;
        atomicAdd(&gacc[p0], gs0);
        atomicAdd(&gacc[p1], gs1);
        #pragma unroll
        for (int k = 0; k < 10; ++k) {
            atomicAdd(&Macc[p0 * 10 + k], am0[k]);
            atomicAdd(&Macc[p1 * 10 + k], am1[k]);
        }
    }
}

// ---- epilogue: per (t-chunk, b) ----
__global__ __launch_bounds__(256) void kC(const float* __restrict__ gacc,
                                          const float* __restrict__ Macc,
                                          const float* __restrict__ b_gate,
                                          const float* __restrict__ b_mlp,
                                          const float* __restrict__ gumbel,
                                          float* __restrict__ out_rs,
                                          float* __restrict__ out_gt,
                                          float* __restrict__ out_pt) {
    __shared__ float spv[5];
    __shared__ float sM[50];
    int tid = threadIdx.x;
    int b = blockIdx.y;
    if (tid < 50) sM[tid] = Macc[b * 50 + tid];
    if (tid < 5) {
        float pv = 1.f / (1.f + __expf(-(gacc[b * 5 + tid] + b_gate[tid])));
        spv[tid] = pv;
        if (blockIdx.x == 0) out_pt[b * 5 + tid] = pv;
    }
    __syncthreads();

    int t = blockIdx.x * 256 + tid;
    if (t >= 1000) return;
    float ex[5], ssum = 0.f;
    #pragma unroll
    for (int c = 0; c < 5; ++c) {
        float2 gu = *(const float2*)&gumbel[(size_t)(((b * 5 + c) * 1000) + t) * 2];
        float arg = (2.f * spv[c] - 1.f + gu.y - gu.x) * 10.0f;  // /tau
        float gt  = 1.f / (1.f + __expf(-arg));
        out_gt[(b * 5 + c) * 1000 + t] = gt;
        float e = __expf(gt);
        ex[c] = e; ssum += e;
    }
    float inv = 1.f / ssum;
    float lg[10];
    #pragma unroll
    for (int k = 0; k < 10; ++k) lg[k] = b_mlp[k];
    #pragma unroll
    for (int c = 0; c < 5; ++c) {
        float v = ex[c] * inv;
        #pragma unroll
        for (int k = 0; k < 10; ++k) lg[k] = fmaf(v, sM[c * 10 + k], lg[k]);
    }
    float mx = 0.f;
    #pragma unroll
    for (int k = 0; k < 10; ++k) { lg[k] = fmaxf(lg[k], 0.f); mx = fmaxf(mx, lg[k]); }
    float se = 0.f;
    #pragma unroll
    for (int k = 0; k < 10; ++k) { lg[k] = __expf(lg[k] - mx); se += lg[k]; }
    float invs = 1.f / se;
    float2 outv[5];
    #pragma unroll
    for (int k = 0; k < 10; ++k) ((float*)outv)[k] = lg[k] * invs;
    float2* dst = (float2*)&out_rs[(size_t)t * 1280 + b * 10];
    #pragma unroll
    for (int j = 0; j < 5; ++j) dst[j] = outv[j];
}

extern "C" void kernel_launch(void* const* d_in, const int* in_sizes, int n_in,
                              void* d_out, int out_size, void* d_ws, size_t ws_size,
                              hipStream_t stream) {
    const float* feats   = (const float*)d_in[0];
    const float* W_adapt = (const float*)d_in[1];
    const float* b_adapt = (const float*)d_in[2];
    const float* W_ch    = (const float*)d_in[3];
    const float* b_ch    = (const float*)d_in[4];
    const float* W_gate  = (const float*)d_in[5];
    const float* b_gate  = (const float*)d_in[6];
    const float* W_mlp   = (const float*)d_in[7];
    const float* b_mlp   = (const float*)d_in[8];
    const float* gumbel  = (const float*)d_in[9];

    float* out    = (float*)d_out;
    float* out_rs = out;                  // (T,B,K)  1,280,000
    float* out_gt = out + 1280000;        // (B,C,T)    640,000
    float* out_pt = out + 1920000;        // (B,C,1)        640

    float* ws   = (float*)d_ws;
    float* pA   = ws;                     // 10*128*512 = 655,360
    float* gacc = pA + 655360;            //     640
    float* Macc = gacc + 640;             //   6,400  (contiguous with gacc)

    kA <<<dim3(32, 10),   256, 0, stream>>>(feats, W_adapt, pA, gacc);
    kG2<<<dim3(16, 4, 5), 256, 0, stream>>>(pA, b_adapt, W_ch, b_ch,
                                            W_gate, W_mlp, gacc, Macc);
    kC <<<dim3(4, 128),   256, 0, stream>>>(gacc, Macc, b_gate, b_mlp, gumbel,
                                            out_rs, out_gt, out_pt);
}

// Round 5
// 56.687 us; speedup vs baseline: 1.2884x; 1.2884x over previous
//
#include <hip/hip_runtime.h>
#include <hip/hip_bf16.h>
#include <math.h>

// B=128, F_IN=1000, D=512, K=10, C=5, T=1000, TAU=0.1
// Contraction: logits_s[b,t,k] = sum_c v[b,c,t]*M[b,c,k], M = h @ W_mlp.
// 5 kernels (split stages, high occupancy, short load loops):
//   kA  : adapt k-split partials pA[s][b][e] (float2 weight loads)
//   kRA : r_b = relu(sum_s pA + b_adapt); init hT[c][b][e] = b_ch[c][e]
//   kB  : channel GEMM d-split; partial sums atomicAdd'ed into hT (no pB)
//   kG  : wave per (b,c): h=relu(hT) -> gate p, M = h@W_mlp (full reduce)
//   kC  : per (b,t): gumbel-sigmoid, softmax_c, MLP, softmax_k

// ---- adapt partials: pA[s][b][e]; s=10 splits of 100 k, 4 b per block ----
__global__ __launch_bounds__(256) void kA(const float* __restrict__ feats,
                                          const float* __restrict__ W_adapt,
                                          float* __restrict__ pA) {
    int b0 = blockIdx.x * 4;          // 32 b-tiles
    int s  = blockIdx.y;              // 10 k-splits
    int k0 = s * 100;
    int e2 = threadIdx.x * 2;         // float2 over e
    float2 acc[4] = {};
    #pragma unroll 2
    for (int k = 0; k < 100; ++k) {
        float2 w = *(const float2*)&W_adapt[(k0 + k) * 512 + e2];
        #pragma unroll
        for (int j = 0; j < 4; ++j) {
            float f = feats[(b0 + j) * 1000 + k0 + k];   // wave-uniform (s_load)
            acc[j].x = fmaf(f, w.x, acc[j].x);
            acc[j].y = fmaf(f, w.y, acc[j].y);
        }
    }
    #pragma unroll
    for (int j = 0; j < 4; ++j)
        *(float2*)&pA[(s * 128 + b0 + j) * 512 + e2] = acc[j];
}

// ---- reduce pA + bias + relu -> r_b; init hT with channel bias ----
__global__ __launch_bounds__(256) void kRA(const float* __restrict__ pA,
                                           const float* __restrict__ b_adapt,
                                           const float* __restrict__ b_ch,
                                           float* __restrict__ r_b,
                                           float* __restrict__ hT) {
    int i = blockIdx.x * 256 + threadIdx.x;   // < 65536
    int e = i & 511;
    float acc = b_adapt[e];
    #pragma unroll
    for (int s = 0; s < 10; ++s) acc += pA[s * 65536 + i];
    r_b[i] = fmaxf(acc, 0.f);
    #pragma unroll
    for (int c = 0; c < 5; ++c) hT[c * 65536 + i] = b_ch[c * 512 + e];
}

// ---- channel GEMM, d-split, atomic accumulate into hT ----
// grid (16 bt, 4 ds, 5 c) = 320 blocks. Per block: 8 b x 512 e x 128 d.
// LDS: r_b slice [8][128]. Per thread: float2 of e, 8 b accums.
__global__ __launch_bounds__(256) void kB(const float* __restrict__ r_b,
                                          const float* __restrict__ W_ch,
                                          float* __restrict__ hT) {
    __shared__ float rbs[8 * 128];
    int b0 = blockIdx.x * 8;
    int d0 = blockIdx.y * 128;
    int c  = blockIdx.z;
    int tid = threadIdx.x;

    #pragma unroll
    for (int it = 0; it < 4; ++it) {
        int idx = it * 256 + tid;            // j*128 + d
        rbs[idx] = r_b[(b0 + (idx >> 7)) * 512 + d0 + (idx & 127)];
    }
    __syncthreads();

    int e2 = tid * 2;
    const float* wb = &W_ch[((size_t)(c * 512 + d0)) * 512 + e2];
    float2 acc[8] = {};
    #pragma unroll 4
    for (int d = 0; d < 128; ++d) {
        float2 w = *(const float2*)&wb[(size_t)d * 512];
        #pragma unroll
        for (int j = 0; j < 8; ++j) {
            float r = rbs[j * 128 + d];      // LDS broadcast (free)
            acc[j].x = fmaf(r, w.x, acc[j].x);
            acc[j].y = fmaf(r, w.y, acc[j].y);
        }
    }
    #pragma unroll
    for (int j = 0; j < 8; ++j) {
        float* dst = &hT[(c * 128 + b0 + j) * 512 + e2];
        atomicAdd(dst,     acc[j].x);
        atomicAdd(dst + 1, acc[j].y);
    }
}

// ---- gate + M: wave per (b,c) ----
__global__ __launch_bounds__(256) void kG(const float* __restrict__ hT,
                                          const float* __restrict__ W_gate,
                                          const float* __restrict__ W_mlp,
                                          const float* __restrict__ b_gate,
                                          float* __restrict__ p,
                                          float* __restrict__ M,
                                          float* __restrict__ out_pt) {
    int wv = threadIdx.x >> 6, lane = threadIdx.x & 63;
    int pair = blockIdx.x * 4 + wv;    // < 640
    int b = pair / 5, c = pair % 5;
    float gs = 0.f, am[10] = {};
    #pragma unroll
    for (int i = 0; i < 8; ++i) {
        int e = i * 64 + lane;
        float h = fmaxf(hT[(c * 128 + b) * 512 + e], 0.f);
        gs = fmaf(h, W_gate[c * 512 + e], gs);
        const float* wm = &W_mlp[e * 10];
        #pragma unroll
        for (int k = 0; k < 10; ++k) am[k] = fmaf(h, wm[k], am[k]);
    }
    #pragma unroll
    for (int off = 32; off; off >>= 1) {
        gs += __shfl_xor(gs, off);
        #pragma unroll
        for (int k = 0; k < 10; ++k) am[k] += __shfl_xor(am[k], off);
    }
    if (lane == 0) {
        float pv = 1.f / (1.f + __expf(-(gs + b_gate[c])));
        p[b * 5 + c] = pv;
        out_pt[b * 5 + c] = pv;
        #pragma unroll
        for (int k = 0; k < 10; ++k) M[(b * 5 + c) * 10 + k] = am[k];
    }
}

// ---- epilogue: per (t-chunk, b) ----
__global__ __launch_bounds__(256) void kC(const float* __restrict__ p,
                                          const float* __restrict__ M,
                                          const float* __restrict__ b_mlp,
                                          const float* __restrict__ gumbel,
                                          float* __restrict__ out_rs,
                                          float* __restrict__ out_gt) {
    __shared__ float spv[5];
    __shared__ float sM[50];
    int tid = threadIdx.x;
    int b = blockIdx.y;
    if (tid < 50) sM[tid] = M[b * 50 + tid];
    if (tid < 5)  spv[tid] = p[b * 5 + tid];
    __syncthreads();

    int t = blockIdx.x * 256 + tid;
    if (t >= 1000) return;
    float ex[5], ssum = 0.f;
    #pragma unroll
    for (int c = 0; c < 5; ++c) {
        float2 gu = *(const float2*)&gumbel[(size_t)(((b * 5 + c) * 1000) + t) * 2];
        float arg = (2.f * spv[c] - 1.f + gu.y - gu.x) * 10.0f;  // /tau
        float gt  = 1.f / (1.f + __expf(-arg));
        out_gt[(b * 5 + c) * 1000 + t] = gt;
        float e = __expf(gt);
        ex[c] = e; ssum += e;
    }
    float inv = 1.f / ssum;
    float lg[10];
    #pragma unroll
    for (int k = 0; k < 10; ++k) lg[k] = b_mlp[k];
    #pragma unroll
    for (int c = 0; c < 5; ++c) {
        float v = ex[c] * inv;
        #pragma unroll
        for (int k = 0; k < 10; ++k) lg[k] = fmaf(v, sM[c * 10 + k], lg[k]);
    }
    float mx = 0.f;
    #pragma unroll
    for (int k = 0; k < 10; ++k) { lg[k] = fmaxf(lg[k], 0.f); mx = fmaxf(mx, lg[k]); }
    float se = 0.f;
    #pragma unroll
    for (int k = 0; k < 10; ++k) { lg[k] = __expf(lg[k] - mx); se += lg[k]; }
    float invs = 1.f / se;
    float2 outv[5];
    #pragma unroll
    for (int k = 0; k < 10; ++k) ((float*)outv)[k] = lg[k] * invs;
    float2* dst = (float2*)&out_rs[(size_t)t * 1280 + b * 10];
    #pragma unroll
    for (int j = 0; j < 5; ++j) dst[j] = outv[j];
}

extern "C" void kernel_launch(void* const* d_in, const int* in_sizes, int n_in,
                              void* d_out, int out_size, void* d_ws, size_t ws_size,
                              hipStream_t stream) {
    const float* feats   = (const float*)d_in[0];
    const float* W_adapt = (const float*)d_in[1];
    const float* b_adapt = (const float*)d_in[2];
    const float* W_ch    = (const float*)d_in[3];
    const float* b_ch    = (const float*)d_in[4];
    const float* W_gate  = (const float*)d_in[5];
    const float* b_gate  = (const float*)d_in[6];
    const float* W_mlp   = (const float*)d_in[7];
    const float* b_mlp   = (const float*)d_in[8];
    const float* gumbel  = (const float*)d_in[9];

    float* out    = (float*)d_out;
    float* out_rs = out;                  // (T,B,K)  1,280,000
    float* out_gt = out + 1280000;        // (B,C,T)    640,000
    float* out_pt = out + 1920000;        // (B,C,1)        640

    float* ws  = (float*)d_ws;
    float* pA  = ws;                      // 10*128*512 = 655,360
    float* r_b = pA + 655360;             //  65,536
    float* hT  = r_b + 65536;             // 5*128*512 = 327,680
    float* p   = hT + 327680;             //     640
    float* M   = p + 640;                 //   6,400

    kA <<<dim3(32, 10),   256, 0, stream>>>(feats, W_adapt, pA);
    kRA<<<256,            256, 0, stream>>>(pA, b_adapt, b_ch, r_b, hT);
    kB <<<dim3(16, 4, 5), 256, 0, stream>>>(r_b, W_ch, hT);
    kG <<<160,            256, 0, stream>>>(hT, W_gate, W_mlp, b_gate, p, M, out_pt);
    kC <<<dim3(4, 128),   256, 0, stream>>>(p, M, b_mlp, gumbel, out_rs, out_gt);
}